// Round 2
// baseline (677.361 us; speedup 1.0000x reference)
//
#include <hip/hip_runtime.h>

typedef unsigned short u16;
typedef unsigned int u32;
typedef __bf16 bf16x8 __attribute__((ext_vector_type(8)));
typedef float f32x4 __attribute__((ext_vector_type(4)));

__device__ __forceinline__ u16 f2b(float f) {
  u32 u = __builtin_bit_cast(u32, f);
  u32 r = (u + 0x7fffu + ((u >> 16) & 1u)) >> 16;  // RNE
  return (u16)r;
}
__device__ __forceinline__ bf16x8 ld_frag(const u16* p) {
  uint4 v = *(const uint4*)p;
  return __builtin_bit_cast(bf16x8, v);
}
// async global->LDS, 16B per lane; lds base must be wave-uniform (HW writes base + lane*16)
__device__ __forceinline__ void async_lds16(const u16* g, u16* lds) {
  __builtin_amdgcn_global_load_lds(
      (const __attribute__((address_space(1))) void*)g,
      (__attribute__((address_space(3))) void*)lds, 16, 0, 0);
}

// ---------------- fp32 -> bf16 bulk convert (x) ----------------
__global__ __launch_bounds__(256) void convert_f32_bf16(const float* __restrict__ in,
                                                        u16* __restrict__ out) {
  long i = ((long)blockIdx.x * 256 + threadIdx.x) * 8;
  float4 a = *(const float4*)(in + i);
  float4 b = *(const float4*)(in + i + 4);
  union { uint4 v; u16 e[8]; } u;
  u.e[0] = f2b(a.x); u.e[1] = f2b(a.y); u.e[2] = f2b(a.z); u.e[3] = f2b(a.w);
  u.e[4] = f2b(b.x); u.e[5] = f2b(b.y); u.e[6] = f2b(b.z); u.e[7] = f2b(b.w);
  *(uint4*)(out + i) = u.v;
}

// ---------------- weight transpose+convert: W_f32[K][N] -> Wt_bf16[N][K] ----------------
__global__ __launch_bounds__(256) void transpose_w(const float* __restrict__ W,
                                                   u16* __restrict__ Wt,
                                                   int K, int N) {
  __shared__ alignas(16) u16 T[64][80];  // pad to 80 u16 (160B rows)
  const int n0 = blockIdx.x * 64, k0 = blockIdx.y * 64;
  const int t = threadIdx.x;
  {
    int kk = t >> 3, c = t & 7;
#pragma unroll
    for (int rr = 0; rr < 2; ++rr) {
      int kr = kk + rr * 32;
      const float* src = W + (long)(k0 + kr) * N + n0 + c * 8;
      float4 a = *(const float4*)src;
      float4 b = *(const float4*)(src + 4);
      u16* dst = &T[kr][c * 8];
      dst[0] = f2b(a.x); dst[1] = f2b(a.y); dst[2] = f2b(a.z); dst[3] = f2b(a.w);
      dst[4] = f2b(b.x); dst[5] = f2b(b.y); dst[6] = f2b(b.z); dst[7] = f2b(b.w);
    }
  }
  __syncthreads();
  {
    int nn = t >> 3, kc = t & 7;
#pragma unroll
    for (int rr = 0; rr < 2; ++rr) {
      int nr = nn + rr * 32;
      union { uint4 v; u16 e[8]; } u;
#pragma unroll
      for (int i = 0; i < 8; ++i) u.e[i] = T[kc * 8 + i][nr];
      *(uint4*)(Wt + (long)(n0 + nr) * K + k0 + kc * 8) = u.v;
    }
  }
}

// ---------------- GEMM: C[M][N] = A_bf16[M][K] * Bt_bf16[N][K]^T + bias_f32 ----------------
// m97 recipe: 128x128 tile, BK=32, 4 waves in 2x2, global_load_lds width=16.
// OUT_F32: store fp32 (final proj) vs bf16 (qkv intermediate).
template <bool OUT_F32>
__global__ __launch_bounds__(256) void gemm_bt(const u16* __restrict__ A,
                                               const u16* __restrict__ Bt,
                                               const float* __restrict__ bias,
                                               void* __restrict__ Cv,
                                               int M, int N, int K) {
  __shared__ alignas(16) u16 As[128 * 32];
  __shared__ alignas(16) u16 Bs[128 * 32];
  const int tid = threadIdx.x;
  const int lane = tid & 63, wave = tid >> 6;
  const int quad = lane >> 4, ln = lane & 15;
  const int wm = wave & 1, wn = wave >> 1;
  const long m0 = (long)blockIdx.y * 128;
  const long n0 = (long)blockIdx.x * 128;

  f32x4 zero = {0.f, 0.f, 0.f, 0.f};
  f32x4 acc[4][4];
#pragma unroll
  for (int i = 0; i < 4; ++i)
#pragma unroll
    for (int j = 0; j < 4; ++j) acc[i][j] = zero;

  // staging chunk c (16B) -> LDS row c>>2, col (c&3)*8; chunk index == byte-offset/16
  const int c1 = tid + 256;
  const int rowA0 = tid >> 2, colA0 = (tid & 3) * 8;
  const int rowA1 = c1 >> 2, colA1 = (c1 & 3) * 8;
  u16* ldsA0 = &As[wave * 512];
  u16* ldsA1 = &As[2048 + wave * 512];
  u16* ldsB0 = &Bs[wave * 512];
  u16* ldsB1 = &Bs[2048 + wave * 512];

  for (int k0 = 0; k0 < K; k0 += 32) {
    async_lds16(A + (m0 + rowA0) * K + k0 + colA0, ldsA0);
    async_lds16(A + (m0 + rowA1) * K + k0 + colA1, ldsA1);
    async_lds16(Bt + (n0 + rowA0) * K + k0 + colA0, ldsB0);
    async_lds16(Bt + (n0 + rowA1) * K + k0 + colA1, ldsB1);
    __builtin_amdgcn_s_waitcnt(0x0f70);  // vmcnt(0)
    __syncthreads();
    bf16x8 af[4], bfr[4];
#pragma unroll
    for (int mt = 0; mt < 4; ++mt)
      af[mt] = ld_frag(&As[(wm * 64 + mt * 16 + ln) * 32 + quad * 8]);
#pragma unroll
    for (int nt = 0; nt < 4; ++nt)
      bfr[nt] = ld_frag(&Bs[(wn * 64 + nt * 16 + ln) * 32 + quad * 8]);
#pragma unroll
    for (int mt = 0; mt < 4; ++mt)
#pragma unroll
      for (int nt = 0; nt < 4; ++nt)
        acc[mt][nt] = __builtin_amdgcn_mfma_f32_16x16x32_bf16(af[mt], bfr[nt], acc[mt][nt], 0, 0, 0);
    __syncthreads();
  }
  // epilogue: C/D layout col=lane&15, row=quad*4+reg (m89/m91 verified)
#pragma unroll
  for (int nt = 0; nt < 4; ++nt) {
    long coln = n0 + wn * 64 + nt * 16 + ln;
    float bv = bias[coln];
#pragma unroll
    for (int mt = 0; mt < 4; ++mt) {
      long rowb = m0 + wm * 64 + mt * 16 + quad * 4;
#pragma unroll
      for (int r = 0; r < 4; ++r) {
        float v = acc[mt][nt][r] + bv;
        if (OUT_F32)
          ((float*)Cv)[(rowb + r) * N + coln] = v;
        else
          ((u16*)Cv)[(rowb + r) * N + coln] = f2b(v);
      }
    }
  }
}

// ---------------- fused attention per (n, head) ----------------
// qkv layout: [n*256 + a][1536], head h occupies cols [h*192, h*192+192): q|k|v of 64 each.
// One block (4 waves) per (n,h). Wave w handles q-rows [w*64, w*64+64) in 2 strips of 32.
__global__ __launch_bounds__(256, 2) void attn_fused(const u16* __restrict__ qkv,
                                                     u16* __restrict__ out) {
  __shared__ alignas(16) u16 Vt[64 * 256];      // V^T, swizzled: (d,j) at [d*256 + ((j+8d)&255)]
  __shared__ alignas(16) u16 Ps[4][16 * 256];   // per-wave P, swizzled rows
  const int h = blockIdx.x;
  const long n = blockIdx.y;
  const int tid = threadIdx.x;
  const int lane = tid & 63, wave = tid >> 6;
  const int quad = lane >> 4, ln = lane & 15;
  const u16* base = qkv + (n * 256) * 1536 + h * 192;

  // stage V^T (transpose 256x64 -> 64x256, swizzled for conflict-free frag reads)
  {
    int p = tid & 7;
    for (int rr = 0; rr < 8; ++rr) {
      int j = (tid >> 3) + rr * 32;
      union { uint4 v; u16 e[8]; } u;
      u.v = *(const uint4*)(base + (long)j * 1536 + 128 + p * 8);
#pragma unroll
      for (int i = 0; i < 8; ++i) {
        int d = p * 8 + i;
        Vt[d * 256 + ((j + 8 * d) & 255)] = u.e[i];
      }
    }
  }
  __syncthreads();

  u16* P = Ps[wave];
  f32x4 zero = {0.f, 0.f, 0.f, 0.f};
  for (int s = 0; s < 2; ++s) {
    const int row0 = wave * 64 + s * 32;
    // q A-frags straight from global: A[m=ln][k=quad*8+i], k-chunks kc*32
    bf16x8 qa[2][2];
#pragma unroll
    for (int mt = 0; mt < 2; ++mt)
#pragma unroll
      for (int kc = 0; kc < 2; ++kc)
        qa[mt][kc] = ld_frag(base + (long)(row0 + mt * 16 + ln) * 1536 + kc * 32 + quad * 8);

    f32x4 sacc[2][16];
#pragma unroll
    for (int mt = 0; mt < 2; ++mt)
#pragma unroll
      for (int jt = 0; jt < 16; ++jt) sacc[mt][jt] = zero;

    // S = q * k^T; k B-frag: B[k=quad*8+i][j=jt*16+ln] read from k-matrix[j][d]
#pragma unroll
    for (int jt = 0; jt < 16; ++jt) {
#pragma unroll
      for (int kc = 0; kc < 2; ++kc) {
        bf16x8 kb = ld_frag(base + (long)(jt * 16 + ln) * 1536 + 64 + kc * 32 + quad * 8);
        sacc[0][jt] = __builtin_amdgcn_mfma_f32_16x16x32_bf16(qa[0][kc], kb, sacc[0][jt], 0, 0, 0);
        sacc[1][jt] = __builtin_amdgcn_mfma_f32_16x16x32_bf16(qa[1][kc], kb, sacc[1][jt], 0, 0, 0);
      }
    }

#pragma unroll
    for (int mt = 0; mt < 2; ++mt) {
      // softmax over j (full 256): rows live at quad*4+r, cols at jt*16+ln
      float linv[4];
#pragma unroll
      for (int r = 0; r < 4; ++r) {
        float mx = -3.0e38f;
#pragma unroll
        for (int jt = 0; jt < 16; ++jt) mx = fmaxf(mx, sacc[mt][jt][r]);
        mx = fmaxf(mx, __shfl_xor(mx, 1));
        mx = fmaxf(mx, __shfl_xor(mx, 2));
        mx = fmaxf(mx, __shfl_xor(mx, 4));
        mx = fmaxf(mx, __shfl_xor(mx, 8));
        float l = 0.f;
#pragma unroll
        for (int jt = 0; jt < 16; ++jt) {
          float p = __expf((sacc[mt][jt][r] - mx) * 0.125f);  // scale^2 = 1/sqrt(64)
          sacc[mt][jt][r] = p;
          l += p;
        }
        l += __shfl_xor(l, 1);
        l += __shfl_xor(l, 2);
        l += __shfl_xor(l, 4);
        l += __shfl_xor(l, 8);
        linv[r] = 1.0f / l;
      }
      // P: C-layout -> LDS (A-layout readable), bf16, swizzled
#pragma unroll
      for (int jt = 0; jt < 16; ++jt)
#pragma unroll
        for (int r = 0; r < 4; ++r) {
          int prow = quad * 4 + r;
          int col = jt * 16 + ln;
          P[prow * 256 + ((col + 8 * prow) & 255)] = f2b(sacc[mt][jt][r]);
        }
      // O = P @ V
      f32x4 oacc[4];
#pragma unroll
      for (int dt = 0; dt < 4; ++dt) oacc[dt] = zero;
#pragma unroll
      for (int jc = 0; jc < 8; ++jc) {
        bf16x8 pa = ld_frag(P + ln * 256 + ((jc * 32 + quad * 8 + 8 * ln) & 255));
#pragma unroll
        for (int dt = 0; dt < 4; ++dt) {
          int d = dt * 16 + ln;
          bf16x8 vb = ld_frag(Vt + d * 256 + ((jc * 32 + quad * 8 + 8 * d) & 255));
          oacc[dt] = __builtin_amdgcn_mfma_f32_16x16x32_bf16(pa, vb, oacc[dt], 0, 0, 0);
        }
      }
      // write attn-out [m][512] at cols h*64 + d
#pragma unroll
      for (int dt = 0; dt < 4; ++dt)
#pragma unroll
        for (int r = 0; r < 4; ++r) {
          long orow = n * 256 + row0 + mt * 16 + quad * 4 + r;
          out[orow * 512 + h * 64 + dt * 16 + ln] = f2b(oacc[dt][r] * linv[r]);
        }
    }
  }
}

extern "C" void kernel_launch(void* const* d_in, const int* in_sizes, int n_in,
                              void* d_out, int out_size, void* d_ws, size_t ws_size,
                              hipStream_t stream) {
  const float* x      = (const float*)d_in[0];  // [65536][512] fp32
  const float* w_qkv  = (const float*)d_in[1];  // [512][1536] fp32
  const float* b_qkv  = (const float*)d_in[2];  // [1536] fp32
  const float* w_proj = (const float*)d_in[3];  // [512][512] fp32
  const float* b_proj = (const float*)d_in[4];  // [512] fp32
  float* out = (float*)d_out;                   // [65536][512] fp32

  char* ws = (char*)d_ws;
  u16* xb   = (u16*)ws;                                   // 64 MiB: x in bf16
  u16* qkv  = (u16*)(ws + 67108864L);                     // 192 MiB: qkv bf16
  u16* attn = (u16*)(ws + 67108864L + 201326592L);        // 64 MiB: attn-out bf16
  u16* Wt1  = (u16*)(ws + 67108864L + 201326592L + 67108864L);  // 1536x512 bf16
  u16* Wt2  = Wt1 + 1536 * 512;                           // 512x512 bf16

  convert_f32_bf16<<<16384, 256, 0, stream>>>(x, xb);
  transpose_w<<<dim3(24, 8), 256, 0, stream>>>(w_qkv, Wt1, 512, 1536);
  transpose_w<<<dim3(8, 8), 256, 0, stream>>>(w_proj, Wt2, 512, 512);
  gemm_bt<false><<<dim3(12, 512), 256, 0, stream>>>(xb, Wt1, b_qkv, qkv, 65536, 1536, 512);
  attn_fused<<<dim3(8, 256), 256, 0, stream>>>(qkv, attn);
  gemm_bt<true><<<dim3(4, 512), 256, 0, stream>>>(attn, Wt2, b_proj, out, 65536, 512, 512);
}

// Round 3
// 559.244 us; speedup vs baseline: 1.2112x; 1.2112x over previous
//
#include <hip/hip_runtime.h>

typedef unsigned short u16;
typedef unsigned int u32;
typedef __bf16 bf16x8 __attribute__((ext_vector_type(8)));
typedef float f32x4 __attribute__((ext_vector_type(4)));

__device__ __forceinline__ u16 f2b(float f) {
  u32 u = __builtin_bit_cast(u32, f);
  u32 r = (u + 0x7fffu + ((u >> 16) & 1u)) >> 16;  // RNE
  return (u16)r;
}
__device__ __forceinline__ bf16x8 ld_frag(const u16* p) {
  uint4 v = *(const uint4*)p;
  return __builtin_bit_cast(bf16x8, v);
}
__device__ __forceinline__ void async_lds16(const u16* g, u16* lds) {
  __builtin_amdgcn_global_load_lds(
      (const __attribute__((address_space(1))) void*)g,
      (__attribute__((address_space(3))) void*)lds, 16, 0, 0);
}
// wait lgkmcnt(0) only (vmcnt=63, expcnt=7 untouched) — needed before
// cross-lane-dependent LDS reads (compiler only tracks same-lane deps)
__device__ __forceinline__ void wait_lds() { __builtin_amdgcn_s_waitcnt(0xc07f); }

// ---------------- fp32 -> bf16 bulk convert (x) ----------------
__global__ __launch_bounds__(256) void convert_f32_bf16(const float* __restrict__ in,
                                                        u16* __restrict__ out) {
  long i = ((long)blockIdx.x * 256 + threadIdx.x) * 8;
  float4 a = *(const float4*)(in + i);
  float4 b = *(const float4*)(in + i + 4);
  union { uint4 v; u16 e[8]; } u;
  u.e[0] = f2b(a.x); u.e[1] = f2b(a.y); u.e[2] = f2b(a.z); u.e[3] = f2b(a.w);
  u.e[4] = f2b(b.x); u.e[5] = f2b(b.y); u.e[6] = f2b(b.z); u.e[7] = f2b(b.w);
  *(uint4*)(out + i) = u.v;
}

// ---------------- weight transpose+convert: W_f32[K][N] -> Wt_bf16[N][K] ----------------
__global__ __launch_bounds__(256) void transpose_w(const float* __restrict__ W,
                                                   u16* __restrict__ Wt,
                                                   int K, int N) {
  __shared__ alignas(16) u16 T[64][80];
  const int n0 = blockIdx.x * 64, k0 = blockIdx.y * 64;
  const int t = threadIdx.x;
  {
    int kk = t >> 3, c = t & 7;
#pragma unroll
    for (int rr = 0; rr < 2; ++rr) {
      int kr = kk + rr * 32;
      const float* src = W + (long)(k0 + kr) * N + n0 + c * 8;
      float4 a = *(const float4*)src;
      float4 b = *(const float4*)(src + 4);
      u16* dst = &T[kr][c * 8];
      dst[0] = f2b(a.x); dst[1] = f2b(a.y); dst[2] = f2b(a.z); dst[3] = f2b(a.w);
      dst[4] = f2b(b.x); dst[5] = f2b(b.y); dst[6] = f2b(b.z); dst[7] = f2b(b.w);
    }
  }
  __syncthreads();
  {
    int nn = t >> 3, kc = t & 7;
#pragma unroll
    for (int rr = 0; rr < 2; ++rr) {
      int nr = nn + rr * 32;
      union { uint4 v; u16 e[8]; } u;
#pragma unroll
      for (int i = 0; i < 8; ++i) u.e[i] = T[kc * 8 + i][nr];
      *(uint4*)(Wt + (long)(n0 + nr) * K + k0 + kc * 8) = u.v;
    }
  }
}

// ---------------- GEMM: C[M][N] = A_bf16[M][K] * Bt_bf16[N][K]^T + bias_f32 ----------------
template <bool OUT_F32>
__global__ __launch_bounds__(256) void gemm_bt(const u16* __restrict__ A,
                                               const u16* __restrict__ Bt,
                                               const float* __restrict__ bias,
                                               void* __restrict__ Cv,
                                               int M, int N, int K) {
  __shared__ alignas(16) u16 As[128 * 32];
  __shared__ alignas(16) u16 Bs[128 * 32];
  const int tid = threadIdx.x;
  const int lane = tid & 63, wave = tid >> 6;
  const int quad = lane >> 4, ln = lane & 15;
  const int wm = wave & 1, wn = wave >> 1;
  const long m0 = (long)blockIdx.y * 128;
  const long n0 = (long)blockIdx.x * 128;

  f32x4 zero = {0.f, 0.f, 0.f, 0.f};
  f32x4 acc[4][4];
#pragma unroll
  for (int i = 0; i < 4; ++i)
#pragma unroll
    for (int j = 0; j < 4; ++j) acc[i][j] = zero;

  const int c1 = tid + 256;
  const int rowA0 = tid >> 2, colA0 = (tid & 3) * 8;
  const int rowA1 = c1 >> 2, colA1 = (c1 & 3) * 8;
  u16* ldsA0 = &As[wave * 512];
  u16* ldsA1 = &As[2048 + wave * 512];
  u16* ldsB0 = &Bs[wave * 512];
  u16* ldsB1 = &Bs[2048 + wave * 512];

  for (int k0 = 0; k0 < K; k0 += 32) {
    async_lds16(A + (m0 + rowA0) * K + k0 + colA0, ldsA0);
    async_lds16(A + (m0 + rowA1) * K + k0 + colA1, ldsA1);
    async_lds16(Bt + (n0 + rowA0) * K + k0 + colA0, ldsB0);
    async_lds16(Bt + (n0 + rowA1) * K + k0 + colA1, ldsB1);
    __builtin_amdgcn_s_waitcnt(0x0f70);  // vmcnt(0)
    __syncthreads();
    bf16x8 af[4], bfr[4];
#pragma unroll
    for (int mt = 0; mt < 4; ++mt)
      af[mt] = ld_frag(&As[(wm * 64 + mt * 16 + ln) * 32 + quad * 8]);
#pragma unroll
    for (int nt = 0; nt < 4; ++nt)
      bfr[nt] = ld_frag(&Bs[(wn * 64 + nt * 16 + ln) * 32 + quad * 8]);
#pragma unroll
    for (int mt = 0; mt < 4; ++mt)
#pragma unroll
      for (int nt = 0; nt < 4; ++nt)
        acc[mt][nt] = __builtin_amdgcn_mfma_f32_16x16x32_bf16(af[mt], bfr[nt], acc[mt][nt], 0, 0, 0);
    __syncthreads();
  }

  if (OUT_F32) {
    // fp32 stores: 16 lanes x 4B = 64B full lines already — direct
#pragma unroll
    for (int nt = 0; nt < 4; ++nt) {
      long coln = n0 + wn * 64 + nt * 16 + ln;
      float bv = bias[coln];
#pragma unroll
      for (int mt = 0; mt < 4; ++mt) {
        long rowb = m0 + wm * 64 + mt * 16 + quad * 4;
#pragma unroll
        for (int r = 0; r < 4; ++r)
          ((float*)Cv)[(rowb + r) * N + coln] = acc[mt][nt][r] + bv;
      }
    }
  } else {
    // bf16: LDS round-trip for full-line 16B stores (kills ~4x write amplification)
    u16* buf = (wm == 0) ? As : Bs;  // [16][136] per wm-group
    for (int mt = 0; mt < 4; ++mt) {
      __syncthreads();
#pragma unroll
      for (int nt = 0; nt < 4; ++nt) {
        long coln = n0 + wn * 64 + nt * 16 + ln;
        float bv = bias[coln];
#pragma unroll
        for (int r = 0; r < 4; ++r)
          buf[(quad * 4 + r) * 136 + wn * 64 + nt * 16 + ln] = f2b(acc[mt][nt][r] + bv);
      }
      __syncthreads();
#pragma unroll
      for (int it = 0; it < 2; ++it) {
        int cid = it * 256 + tid;
        int bufi = cid >> 8, row = (cid >> 4) & 15, ch = cid & 15;
        const u16* sb = bufi ? Bs : As;
        uint4 v = *(const uint4*)&sb[row * 136 + ch * 8];
        *(uint4*)&((u16*)Cv)[(m0 + (long)bufi * 64 + mt * 16 + row) * N + n0 + ch * 8] = v;
      }
    }
  }
}

// ---------------- fused attention per (n, head) ----------------
// qkv row layout [1536]: head h cols [h*192, +192) = q|k|v of 64.
// Block = 4 waves; wave w, strip s handles q-rows [w*64+s*32, +32).
// LDS: Ks [256][64] + Vt [64][256] = 64 KB; P aliases Ks during PV (waves
// are locksteppped by __syncthreads; K re-staged between strips).
__global__ __launch_bounds__(256, 2) void attn_fused(const u16* __restrict__ qkv,
                                                     u16* __restrict__ out) {
  __shared__ alignas(16) u16 Ks[256 * 64];  // [j][64], 16B chunk c stored at c^(j&7)
  __shared__ alignas(16) u16 Vt[64 * 256];  // [d][256], chunk cj stored at cj^(((d>>3)^d)&7)
  const int h = blockIdx.x;
  const long n = blockIdx.y;
  const int tid = threadIdx.x;
  const int lane = tid & 63, wave = tid >> 6;
  const int quad = lane >> 4, ln = lane & 15;
  const u16* base = qkv + (n * 256) * 1536 + h * 192;

  // ---- stage K (coalesced 16B loads; swizzled 16B LDS writes, conflict-free) ----
  auto stageK = [&]() {
    int c = tid & 7, jb = tid >> 3;
#pragma unroll
    for (int rr = 0; rr < 8; ++rr) {
      int j = jb + rr * 32;
      uint4 v = *(const uint4*)(base + (long)j * 1536 + 64 + c * 8);
      *(uint4*)&Ks[j * 64 + ((c ^ (j & 7)) * 8)] = v;
    }
  };
  stageK();
  // ---- stage V^T (coalesced loads; scalar scatter, key=(p^i) -> conflict-free) ----
  {
    int p = tid & 7, jb = tid >> 3;
#pragma unroll
    for (int rr = 0; rr < 8; ++rr) {
      int j = jb + rr * 32;
      union { uint4 v; u16 e[8]; } u;
      u.v = *(const uint4*)(base + (long)j * 1536 + 128 + p * 8);
      int cj = j >> 3, jl = j & 7;
#pragma unroll
      for (int i = 0; i < 8; ++i) {
        int d = p * 8 + i;
        int key = (p ^ i) & 7;  // == ((d>>3)^d)&7
        Vt[d * 256 + ((cj ^ key) * 8) + jl] = u.e[i];
      }
    }
  }
  __syncthreads();

  u16* Pw = &Ks[wave * 2176];  // [16][136] u16, aliases Ks during PV phases
  f32x4 zero = {0.f, 0.f, 0.f, 0.f};

  for (int s = 0; s < 2; ++s) {
    const int row0 = wave * 64 + s * 32;
    // q A-frags from global (rows x 64B lines, read once — coalesced)
    bf16x8 qa[2][2];
#pragma unroll
    for (int mt = 0; mt < 2; ++mt)
#pragma unroll
      for (int kc = 0; kc < 2; ++kc)
        qa[mt][kc] = ld_frag(base + (long)(row0 + mt * 16 + ln) * 1536 + kc * 32 + quad * 8);

    f32x4 sacc[2][16];
#pragma unroll
    for (int mt = 0; mt < 2; ++mt)
#pragma unroll
      for (int jt = 0; jt < 16; ++jt) sacc[mt][jt] = zero;

    // S = q k^T, kb from swizzled LDS
#pragma unroll
    for (int jt = 0; jt < 16; ++jt) {
#pragma unroll
      for (int kc = 0; kc < 2; ++kc) {
        bf16x8 kb = ld_frag(&Ks[(jt * 16 + ln) * 64 + (((kc * 4 + quad) ^ (ln & 7)) * 8)]);
        sacc[0][jt] = __builtin_amdgcn_mfma_f32_16x16x32_bf16(qa[0][kc], kb, sacc[0][jt], 0, 0, 0);
        sacc[1][jt] = __builtin_amdgcn_mfma_f32_16x16x32_bf16(qa[1][kc], kb, sacc[1][jt], 0, 0, 0);
      }
    }
    __syncthreads();  // all waves done reading Ks -> P may alias it

#pragma unroll
    for (int mt = 0; mt < 2; ++mt) {
      // softmax over j (rows at quad*4+r, cols at jt*16+ln)
      float linv[4];
#pragma unroll
      for (int r = 0; r < 4; ++r) {
        float mx = -3.0e38f;
#pragma unroll
        for (int jt = 0; jt < 16; ++jt) mx = fmaxf(mx, sacc[mt][jt][r]);
        mx = fmaxf(mx, __shfl_xor(mx, 1));
        mx = fmaxf(mx, __shfl_xor(mx, 2));
        mx = fmaxf(mx, __shfl_xor(mx, 4));
        mx = fmaxf(mx, __shfl_xor(mx, 8));
        float l = 0.f;
#pragma unroll
        for (int jt = 0; jt < 16; ++jt) {
          float p = __expf((sacc[mt][jt][r] - mx) * 0.125f);  // 1/sqrt(dh)
          sacc[mt][jt][r] = p;
          l += p;
        }
        l += __shfl_xor(l, 1);
        l += __shfl_xor(l, 2);
        l += __shfl_xor(l, 4);
        l += __shfl_xor(l, 8);
        linv[r] = 1.0f / l;
      }

      // O = P V in two j-halves of 128 (P buffer reused; oacc accumulates)
      f32x4 oacc[4];
#pragma unroll
      for (int dt = 0; dt < 4; ++dt) oacc[dt] = zero;
#pragma unroll
      for (int jh = 0; jh < 2; ++jh) {
#pragma unroll
        for (int jl = 0; jl < 8; ++jl) {
          int jt = jh * 8 + jl;
#pragma unroll
          for (int r = 0; r < 4; ++r)
            Pw[(quad * 4 + r) * 136 + jl * 16 + ln] = f2b(sacc[mt][jt][r]);
        }
        wait_lds();  // cross-lane LDS RAW
#pragma unroll
        for (int jcl = 0; jcl < 4; ++jcl) {
          bf16x8 pa = ld_frag(&Pw[ln * 136 + jcl * 32 + quad * 8]);
          int cjb = (jh * 4 + jcl) * 4 + quad;
#pragma unroll
          for (int dt = 0; dt < 4; ++dt) {
            int d = dt * 16 + ln;
            int key = ((d >> 3) ^ d) & 7;
            bf16x8 vb = ld_frag(&Vt[d * 256 + ((cjb ^ key) * 8)]);
            oacc[dt] = __builtin_amdgcn_mfma_f32_16x16x32_bf16(pa, vb, oacc[dt], 0, 0, 0);
          }
        }
      }
      // stage O tile (16 x 64) into Pw, then coalesced 16B global stores
#pragma unroll
      for (int dt = 0; dt < 4; ++dt)
#pragma unroll
        for (int r = 0; r < 4; ++r)
          Pw[(quad * 4 + r) * 136 + dt * 16 + ln] = f2b(oacc[dt][r] * linv[r]);
      wait_lds();
#pragma unroll
      for (int it = 0; it < 2; ++it) {
        int cid = it * 64 + lane;
        int row = cid >> 3, ch = cid & 7;
        uint4 v = *(const uint4*)&Pw[row * 136 + ch * 8];
        *(uint4*)&out[(n * 256 + row0 + mt * 16 + row) * 512 + h * 64 + ch * 8] = v;
      }
    }
    __syncthreads();  // P region quiesced
    if (s == 0) {
      stageK();       // restore K for strip 1
      __syncthreads();
    }
  }
}

extern "C" void kernel_launch(void* const* d_in, const int* in_sizes, int n_in,
                              void* d_out, int out_size, void* d_ws, size_t ws_size,
                              hipStream_t stream) {
  const float* x      = (const float*)d_in[0];  // [65536][512] fp32
  const float* w_qkv  = (const float*)d_in[1];  // [512][1536]
  const float* b_qkv  = (const float*)d_in[2];  // [1536]
  const float* w_proj = (const float*)d_in[3];  // [512][512]
  const float* b_proj = (const float*)d_in[4];  // [512]
  float* out = (float*)d_out;                   // [65536][512] fp32

  char* ws = (char*)d_ws;
  u16* xb   = (u16*)ws;                                         // 64 MiB
  u16* qkv  = (u16*)(ws + 67108864L);                           // 192 MiB
  u16* attn = (u16*)(ws + 67108864L + 201326592L);              // 64 MiB
  u16* Wt1  = (u16*)(ws + 67108864L + 201326592L + 67108864L);  // 1536x512
  u16* Wt2  = Wt1 + 1536 * 512;                                 // 512x512

  convert_f32_bf16<<<16384, 256, 0, stream>>>(x, xb);
  transpose_w<<<dim3(24, 8), 256, 0, stream>>>(w_qkv, Wt1, 512, 1536);
  transpose_w<<<dim3(8, 8), 256, 0, stream>>>(w_proj, Wt2, 512, 512);
  gemm_bt<false><<<dim3(12, 512), 256, 0, stream>>>(xb, Wt1, b_qkv, qkv, 65536, 1536, 512);
  attn_fused<<<dim3(8, 256), 256, 0, stream>>>(qkv, attn);
  gemm_bt<true><<<dim3(4, 512), 256, 0, stream>>>(attn, Wt2, b_proj, out, 65536, 512, 512);
}